// Round 1
// baseline (117.881 us; speedup 1.0000x reference)
//
#include <hip/hip_runtime.h>
#include <hip/hip_bf16.h>

// Problem constants (B=2, M=2048, HS=1024, K=16 heads, D=64)
#define MM   2048
#define HSZ  1024
#define KH   16
#define DH   64

typedef __attribute__((ext_vector_type(8))) short bf16x8;
typedef __attribute__((ext_vector_type(4))) float f32x4;
typedef __attribute__((ext_vector_type(8))) unsigned short u16x8;

__device__ __forceinline__ unsigned short f2bf(float x) {
    union { float f; unsigned u; } v; v.f = x;
    unsigned r = v.u + 0x7FFFu + ((v.u >> 16) & 1u);
    return (unsigned short)(r >> 16);
}

// ---------------- f32 -> bf16 convert (vectorized) ----------------
__global__ void cvt_bf16(const float* __restrict__ in, unsigned short* __restrict__ out, int n) {
    int i = (blockIdx.x * blockDim.x + threadIdx.x) * 4;
    if (i < n) {
        float4 v = *(const float4*)(in + i);
        ushort4 o;
        o.x = f2bf(v.x); o.y = f2bf(v.y); o.z = f2bf(v.z); o.w = f2bf(v.w);
        *(ushort4*)(out + i) = o;
    }
}

// ---------------- span projection: mean/soft per (head,row) ----------------
// proj[b,m,o] = h[b,m,:] . W_span[o,:]  (o = 0..31)
// mean[b*16+k][m] = sigmoid(proj[2k]) * 2048 ; soft[...] = softplus(proj[2k+1])
__global__ __launch_bounds__(256) void span_proj(
    const float* __restrict__ h, const float* __restrict__ Wspan,
    float* __restrict__ mean_, float* __restrict__ soft_)
{
    __shared__ float hrow[HSZ];
    int row = blockIdx.x;            // b*2048 + m
    int b = row >> 11, m = row & 2047;
    int t = threadIdx.x;
    *(float4*)&hrow[t * 4] = *(const float4*)&h[(long)row * HSZ + t * 4];
    __syncthreads();
    int o = t >> 3, part = t & 7;    // 32 outputs x 8 threads
    const float* w = Wspan + o * HSZ;
    float4 s4 = {0.f, 0.f, 0.f, 0.f};
    #pragma unroll 8
    for (int i = 0; i < 32; ++i) {
        int c = part * 4 + i * 32;
        float4 a  = *(const float4*)&hrow[c];
        float4 wv = *(const float4*)&w[c];
        s4.x += a.x * wv.x; s4.y += a.y * wv.y;
        s4.z += a.z * wv.z; s4.w += a.w * wv.w;
    }
    float s = s4.x + s4.y + s4.z + s4.w;
    s += __shfl_xor(s, 1, 64);
    s += __shfl_xor(s, 2, 64);
    s += __shfl_xor(s, 4, 64);
    if (part == 0) {
        int k = o >> 1;
        int bk = b * KH + k;
        if ((o & 1) == 0) {
            mean_[bk * MM + m] = (1.f / (1.f + __expf(-s))) * (float)MM;
        } else {
            float sp = (s > 15.f) ? s : log1pf(__expf(s));
            soft_[bk * MM + m] = sp;
        }
    }
}

// ---------------- bf16 MFMA GEMM: C[i,j] = sum_k A[i,k]*B[j,k] ----------------
// A: [Mr, Kd] bf16 row-major, B: [N, Kd] bf16 row-major, C: [Mr, N] (f32 or bf16)
// 128x128 tile, BK=64, 256 threads (4 waves, each 64x64)
template<int STORE_BF16>
__global__ __launch_bounds__(256) void gemm_bt(
    const unsigned short* __restrict__ A, const unsigned short* __restrict__ Bm,
    void* __restrict__ Cv, int Mr, int N, int Kd,
    long aZ, long bZ, long cZ)
{
    __shared__ unsigned short As[128][72];   // 64 + 8 pad (16B) -> conflict-light
    __shared__ unsigned short Bs[128][72];
    const unsigned short* Ab = A  + blockIdx.z * aZ;
    const unsigned short* Bb = Bm + blockIdx.z * bZ;
    long czoff = blockIdx.z * cZ;
    int row0 = blockIdx.y * 128;
    int col0 = blockIdx.x * 128;
    int t = threadIdx.x;
    int wid = t >> 6, l = t & 63;
    int wr = wid >> 1, wc = wid & 1;
    int lr = l & 15, lhi = l >> 4;

    f32x4 acc[4][4] = {};

    for (int k0 = 0; k0 < Kd; k0 += 64) {
        __syncthreads();
        #pragma unroll
        for (int i = 0; i < 4; ++i) {
            int c = t + 256 * i;           // 0..1023 chunk id
            int r = c >> 3, c8 = (c & 7) * 8;
            u16x8 va = *(const u16x8*)(Ab + (long)(row0 + r) * Kd + k0 + c8);
            *(u16x8*)&As[r][c8] = va;
            u16x8 vb = *(const u16x8*)(Bb + (long)(col0 + r) * Kd + k0 + c8);
            *(u16x8*)&Bs[r][c8] = vb;
        }
        __syncthreads();
        #pragma unroll
        for (int kk = 0; kk < 64; kk += 32) {
            int lc = kk + lhi * 8;
            bf16x8 af[4], bfr[4];
            #pragma unroll
            for (int i = 0; i < 4; ++i)
                af[i] = *(const bf16x8*)&As[wr * 64 + i * 16 + lr][lc];
            #pragma unroll
            for (int j = 0; j < 4; ++j)
                bfr[j] = *(const bf16x8*)&Bs[wc * 64 + j * 16 + lr][lc];
            #pragma unroll
            for (int i = 0; i < 4; ++i)
                #pragma unroll
                for (int j = 0; j < 4; ++j)
                    acc[i][j] = __builtin_amdgcn_mfma_f32_16x16x32_bf16(af[i], bfr[j], acc[i][j], 0, 0, 0);
        }
    }

    // C/D layout: col = l&15, row = (l>>4)*4 + r_
    #pragma unroll
    for (int i = 0; i < 4; ++i) {
        int rbase = row0 + wr * 64 + i * 16 + lhi * 4;
        #pragma unroll
        for (int j = 0; j < 4; ++j) {
            int cidx = col0 + wc * 64 + j * 16 + lr;
            #pragma unroll
            for (int r_ = 0; r_ < 4; ++r_) {
                long idx = czoff + (long)(rbase + r_) * N + cidx;
                if (STORE_BF16) ((unsigned short*)Cv)[idx] = f2bf(acc[i][j][r_]);
                else            ((float*)Cv)[idx] = acc[i][j][r_];
            }
        }
    }
}

// ---------------- fused Gaussian attention: out = softmax(-soft*(j-mean)^2) @ V ----------------
// hvT: [32 heads * 64 d][2048 j] bf16 (K-major V).  att out: (B, M, HS) bf16.
// Block: 256 thr (4 waves), head = blockIdx.y, 64 q-rows (16/wave). k-tiles of 32.
__global__ __launch_bounds__(256) void attn_gauss(
    const float* __restrict__ mean_, const float* __restrict__ soft_,
    const unsigned short* __restrict__ hvT, unsigned short* __restrict__ att)
{
    __shared__ unsigned short Vs[64][40];    // [d][k] pad 40 -> conflict-free b128 reads
    int qb = blockIdx.x;                     // 0..31
    int bk = blockIdx.y;                     // 0..31  (= b*16 + head)
    int t = threadIdx.x, wid = t >> 6, l = t & 63;
    int b = bk >> 4, head = bk & 15;
    int lr = l & 15, lhi = l >> 4;
    int q = qb * 64 + wid * 16 + lr;
    float mq  = mean_[bk * MM + q];
    float sq  = soft_[bk * MM + q];
    const unsigned short* Vbase = hvT + (long)bk * DH * MM;

    f32x4 acc[4] = {};
    float lsum = 0.f;
    int jlane0 = lhi * 8;
    int sd = t >> 2, sc8 = (t & 3) * 8;      // staging: d-row, k-chunk

    for (int kt = 0; kt < 64; ++kt) {
        int k0 = kt * 32;
        __syncthreads();
        *(u16x8*)&Vs[sd][sc8] = *(const u16x8*)(Vbase + (long)sd * MM + k0 + sc8);
        __syncthreads();

        // skip tiles with negligible weight for ALL 16 rows of this wave
        float dmin = fmaxf(fmaxf((float)k0 - mq, mq - (float)(k0 + 31)), 0.f);
        bool active = (sq * dmin * dmin) < 50.f;   // exp(-50) ~ 2e-22: exact-0 territory
        if (__ballot(active)) {
            bf16x8 pfrag;
            #pragma unroll
            for (int jj = 0; jj < 8; ++jj) {
                float jf = (float)(k0 + jlane0 + jj);
                float d_ = jf - mq;
                float p = __expf(-sq * d_ * d_);
                lsum += p;
                pfrag[jj] = (short)f2bf(p);
            }
            #pragma unroll
            for (int df = 0; df < 4; ++df) {
                bf16x8 vf = *(const bf16x8*)&Vs[df * 16 + lr][jlane0];
                acc[df] = __builtin_amdgcn_mfma_f32_16x16x32_bf16(pfrag, vf, acc[df], 0, 0, 0);
            }
        }
    }

    // row-sum: lanes {q, q+16, q+32, q+48} hold partials
    lsum += __shfl_xor(lsum, 16, 64);
    lsum += __shfl_xor(lsum, 32, 64);

    int qrow_base = qb * 64 + wid * 16;
    #pragma unroll
    for (int r_ = 0; r_ < 4; ++r_) {
        int qr = lhi * 4 + r_;
        float inv = 1.f / __shfl(lsum, qr, 64);
        long orow = ((long)b * MM + (qrow_base + qr)) * HSZ + head * DH;
        #pragma unroll
        for (int df = 0; df < 4; ++df)
            att[orow + df * 16 + lr] = f2bf(acc[df][r_] * inv);
    }
}

extern "C" void kernel_launch(void* const* d_in, const int* in_sizes, int n_in,
                              void* d_out, int out_size, void* d_ws, size_t ws_size,
                              hipStream_t stream) {
    (void)in_sizes; (void)n_in; (void)out_size; (void)ws_size;
    const float* h     = (const float*)d_in[0];   // (2, 2048, 1024)
    const float* Wspan = (const float*)d_in[1];   // (32, 1024)
    const float* Wval  = (const float*)d_in[2];   // (1024, 1024)
    const float* Wout  = (const float*)d_in[3];   // (1024, 1024)
    float* out = (float*)d_out;                   // (2, 2048, 1024) f32

    char* ws = (char*)d_ws;
    unsigned short* h_bf    = (unsigned short*)(ws);               // 8 MB
    unsigned short* Wval_bf = (unsigned short*)(ws +  8388608);    // 2 MB
    unsigned short* Wout_bf = (unsigned short*)(ws + 10485760);    // 2 MB
    unsigned short* hvT     = (unsigned short*)(ws + 12582912);    // 8 MB  [b*1024 + head*64 + d][m]
    unsigned short* att     = (unsigned short*)(ws + 20971520);    // 8 MB  (B, M, HS)
    float*          mean_   = (float*)(ws + 29360128);             // 256 KB
    float*          soft_   = (float*)(ws + 29622272);             // 256 KB

    // converts
    cvt_bf16<<<4096, 256, 0, stream>>>(h,    h_bf,    2 * MM * HSZ);
    cvt_bf16<<<1024, 256, 0, stream>>>(Wval, Wval_bf, HSZ * HSZ);
    cvt_bf16<<<1024, 256, 0, stream>>>(Wout, Wout_bf, HSZ * HSZ);

    // span params
    span_proj<<<2 * MM, 256, 0, stream>>>(h, Wspan, mean_, soft_);

    // value GEMM, transposed output: hvT[b*1024 + n][m] = sum_c Wval[n,c] * h[b,m,c]
    gemm_bt<1><<<dim3(MM / 128, HSZ / 128, 2), 256, 0, stream>>>(
        Wval_bf, h_bf, hvT, HSZ, MM, HSZ,
        0L, (long)MM * HSZ, (long)HSZ * MM);

    // fused Gaussian attention -> att (B, M, HS) bf16
    attn_gauss<<<dim3(MM / 64, 32), 256, 0, stream>>>(mean_, soft_, hvT, att);

    // output GEMM: out[b*2048+m][n] = sum_c att[b,m,c] * Wout[n,c]
    gemm_bt<0><<<dim3(HSZ / 128, (2 * MM) / 128, 1), 256, 0, stream>>>(
        att, Wout_bf, out, 2 * MM, HSZ, HSZ,
        0L, 0L, 0L);
}

// Round 2
// 110.230 us; speedup vs baseline: 1.0694x; 1.0694x over previous
//
#include <hip/hip_runtime.h>
#include <hip/hip_bf16.h>

// Problem constants (B=2, M=2048, HS=1024, K=16 heads, D=64)
#define MM   2048
#define HSZ  1024
#define KH   16
#define DH   64

typedef __attribute__((ext_vector_type(8))) short bf16x8;
typedef __attribute__((ext_vector_type(4))) float f32x4;
typedef __attribute__((ext_vector_type(8))) unsigned short u16x8;

#define GLOAD_LDS16(gp, lp) \
    __builtin_amdgcn_global_load_lds( \
        (const __attribute__((address_space(1))) unsigned int*)(gp), \
        (__attribute__((address_space(3))) unsigned int*)(lp), 16, 0, 0)

__device__ __forceinline__ unsigned short f2bf(float x) {
    union { float f; unsigned u; } v; v.f = x;
    unsigned r = v.u + 0x7FFFu + ((v.u >> 16) & 1u);
    return (unsigned short)(r >> 16);
}

// ---------------- weight converts, both in one launch ----------------
__global__ void cvt_w(const float* __restrict__ w0, const float* __restrict__ w1,
                      unsigned short* __restrict__ o0, unsigned short* __restrict__ o1) {
    int bid = blockIdx.x;
    const float* in = (bid < 1024) ? w0 : w1;
    unsigned short* out = (bid < 1024) ? o0 : o1;
    int i = ((bid & 1023) * 256 + threadIdx.x) * 4;
    float4 v = *(const float4*)(in + i);
    ushort4 o;
    o.x = f2bf(v.x); o.y = f2bf(v.y); o.z = f2bf(v.z); o.w = f2bf(v.w);
    *(ushort4*)(out + i) = o;
}

// ---------------- span projection (+ fused h f32->bf16 convert) ----------------
__global__ __launch_bounds__(256) void span_proj(
    const float* __restrict__ h, const float* __restrict__ Wspan,
    float* __restrict__ mean_, float* __restrict__ soft_,
    unsigned short* __restrict__ h_bf)
{
    __shared__ float hrow[HSZ];
    int row = blockIdx.x;            // b*2048 + m
    int b = row >> 11, m = row & 2047;
    int t = threadIdx.x;
    float4 hv = *(const float4*)&h[(long)row * HSZ + t * 4];
    *(float4*)&hrow[t * 4] = hv;
    // fused convert: write h_bf
    ushort4 hb;
    hb.x = f2bf(hv.x); hb.y = f2bf(hv.y); hb.z = f2bf(hv.z); hb.w = f2bf(hv.w);
    *(ushort4*)&h_bf[(long)row * HSZ + t * 4] = hb;
    __syncthreads();
    int o = t >> 3, part = t & 7;    // 32 outputs x 8 threads
    const float* w = Wspan + o * HSZ;
    float4 s4 = {0.f, 0.f, 0.f, 0.f};
    #pragma unroll 8
    for (int i = 0; i < 32; ++i) {
        int c = part * 4 + i * 32;
        float4 a  = *(const float4*)&hrow[c];
        float4 wv = *(const float4*)&w[c];
        s4.x += a.x * wv.x; s4.y += a.y * wv.y;
        s4.z += a.z * wv.z; s4.w += a.w * wv.w;
    }
    float s = s4.x + s4.y + s4.z + s4.w;
    s += __shfl_xor(s, 1, 64);
    s += __shfl_xor(s, 2, 64);
    s += __shfl_xor(s, 4, 64);
    if (part == 0) {
        int k = o >> 1;
        int bk = b * KH + k;
        if ((o & 1) == 0) {
            mean_[bk * MM + m] = (1.f / (1.f + __expf(-s))) * (float)MM;
        } else {
            float sp = (s > 15.f) ? s : log1pf(__expf(s));
            soft_[bk * MM + m] = sp;
        }
    }
}

// ---------------- bf16 MFMA GEMM: C[i,j] = sum_k A[i,k]*B[j,k] ----------------
// 128(M) x 64(N) tile, BK=64, 256 threads (4 waves, each 64x32 out).
// m97-style staging: global_load_lds width-16, linear LDS.
template<int STORE_BF16>
__global__ __launch_bounds__(256) void gemm_bt(
    const unsigned short* __restrict__ A, const unsigned short* __restrict__ Bm,
    void* __restrict__ Cv, int N, int Kd,
    long aZ, long bZ, long cZ)
{
    __shared__ __align__(16) unsigned short As[128 * 64];
    __shared__ __align__(16) unsigned short Bs[64 * 64];
    const unsigned short* Ab = A  + blockIdx.z * aZ;
    const unsigned short* Bb = Bm + blockIdx.z * bZ;
    long czoff = blockIdx.z * cZ;
    int row0 = blockIdx.y * 128;
    int col0 = blockIdx.x * 64;
    int t = threadIdx.x;
    int wid = t >> 6, l = t & 63;
    int wr = wid >> 1, wc = wid & 1;
    int lr = l & 15, lhi = l >> 4;

    f32x4 acc[4][2] = {};

    for (int k0 = 0; k0 < Kd; k0 += 64) {
        __syncthreads();
        #pragma unroll
        for (int i = 0; i < 4; ++i) {
            int c = t + 256 * i;               // 0..1023: A tile chunks
            int r = c >> 3, c8 = (c & 7) * 8;
            GLOAD_LDS16(Ab + (long)(row0 + r) * Kd + k0 + c8, &As[c * 8]);
        }
        #pragma unroll
        for (int i = 0; i < 2; ++i) {
            int c = t + 256 * i;               // 0..511: B tile chunks
            int r = c >> 3, c8 = (c & 7) * 8;
            GLOAD_LDS16(Bb + (long)(col0 + r) * Kd + k0 + c8, &Bs[c * 8]);
        }
        __syncthreads();
        #pragma unroll
        for (int kk = 0; kk < 64; kk += 32) {
            int lc = kk + lhi * 8;
            bf16x8 af[4], bfr[2];
            #pragma unroll
            for (int i = 0; i < 4; ++i)
                af[i] = *(const bf16x8*)&As[(wr * 64 + i * 16 + lr) * 64 + lc];
            #pragma unroll
            for (int j = 0; j < 2; ++j)
                bfr[j] = *(const bf16x8*)&Bs[(wc * 32 + j * 16 + lr) * 64 + lc];
            #pragma unroll
            for (int i = 0; i < 4; ++i)
                #pragma unroll
                for (int j = 0; j < 2; ++j)
                    acc[i][j] = __builtin_amdgcn_mfma_f32_16x16x32_bf16(af[i], bfr[j], acc[i][j], 0, 0, 0);
        }
    }

    // C/D layout: col = l&15, row = (l>>4)*4 + r_
    #pragma unroll
    for (int i = 0; i < 4; ++i) {
        int rbase = row0 + wr * 64 + i * 16 + lhi * 4;
        #pragma unroll
        for (int j = 0; j < 2; ++j) {
            int cidx = col0 + wc * 32 + j * 16 + lr;
            #pragma unroll
            for (int r_ = 0; r_ < 4; ++r_) {
                long idx = czoff + (long)(rbase + r_) * N + cidx;
                if (STORE_BF16) ((unsigned short*)Cv)[idx] = f2bf(acc[i][j][r_]);
                else            ((float*)Cv)[idx] = acc[i][j][r_];
            }
        }
    }
}

// ---------------- fused Gaussian attention: out = softmax(-soft*(j-mean)^2) @ V ----------------
// hvT: [b*1024 + head*64 + d][2048 j] bf16 (K-major V).  att out: (B, M, HS) bf16.
// Block: 256 thr (4 waves), 64 q-rows (16/wave), k-tiles of 64 (2 MFMA K-steps each).
__global__ __launch_bounds__(256) void attn_gauss(
    const float* __restrict__ mean_, const float* __restrict__ soft_,
    const unsigned short* __restrict__ hvT, unsigned short* __restrict__ att)
{
    __shared__ unsigned short Vs[64][72];    // [d][k] +8 pad -> conflict-light b128 reads
    int qb = blockIdx.x;                     // 0..31
    int bk = blockIdx.y;                     // 0..31  (= b*16 + head)
    int t = threadIdx.x, wid = t >> 6, l = t & 63;
    int b = bk >> 4, head = bk & 15;
    int lr = l & 15, lhi = l >> 4;
    int q = qb * 64 + wid * 16 + lr;
    float mq  = mean_[bk * MM + q];
    float sq  = soft_[bk * MM + q];
    const unsigned short* Vbase = hvT + (long)bk * DH * MM;

    f32x4 acc[4] = {};
    float lsum = 0.f;
    int jlane0 = lhi * 8;

    for (int kt = 0; kt < 32; ++kt) {
        int k0 = kt * 64;
        __syncthreads();
        #pragma unroll
        for (int i = 0; i < 2; ++i) {
            int c = t + 256 * i;               // 0..511
            int d = c >> 3, c8 = (c & 7) * 8;
            *(u16x8*)&Vs[d][c8] = *(const u16x8*)(Vbase + (long)d * MM + k0 + c8);
        }
        __syncthreads();

        // skip tiles negligible for ALL 16 rows of this wave
        float dmin = fmaxf(fmaxf((float)k0 - mq, mq - (float)(k0 + 63)), 0.f);
        bool active = (sq * dmin * dmin) < 50.f;   // exp(-50) ~ 2e-22
        if (__ballot(active)) {
            #pragma unroll
            for (int kk = 0; kk < 64; kk += 32) {
                bf16x8 pfrag;
                float dbase = (float)(k0 + kk + jlane0) - mq;
                #pragma unroll
                for (int jj = 0; jj < 8; ++jj) {
                    float d_ = dbase + (float)jj;
                    float p = __expf(-sq * d_ * d_);
                    lsum += p;
                    pfrag[jj] = (short)f2bf(p);
                }
                #pragma unroll
                for (int df = 0; df < 4; ++df) {
                    bf16x8 vf = *(const bf16x8*)&Vs[df * 16 + lr][kk + jlane0];
                    acc[df] = __builtin_amdgcn_mfma_f32_16x16x32_bf16(pfrag, vf, acc[df], 0, 0, 0);
                }
            }
        }
    }

    // row-sum: lanes {q, q+16, q+32, q+48} hold partials
    lsum += __shfl_xor(lsum, 16, 64);
    lsum += __shfl_xor(lsum, 32, 64);

    int qrow_base = qb * 64 + wid * 16;
    #pragma unroll
    for (int r_ = 0; r_ < 4; ++r_) {
        int qr = lhi * 4 + r_;
        float inv = 1.f / __shfl(lsum, qr, 64);
        long orow = ((long)b * MM + (qrow_base + qr)) * HSZ + head * DH;
        #pragma unroll
        for (int df = 0; df < 4; ++df)
            att[orow + df * 16 + lr] = f2bf(acc[df][r_] * inv);
    }
}

extern "C" void kernel_launch(void* const* d_in, const int* in_sizes, int n_in,
                              void* d_out, int out_size, void* d_ws, size_t ws_size,
                              hipStream_t stream) {
    (void)in_sizes; (void)n_in; (void)out_size; (void)ws_size;
    const float* h     = (const float*)d_in[0];   // (2, 2048, 1024)
    const float* Wspan = (const float*)d_in[1];   // (32, 1024)
    const float* Wval  = (const float*)d_in[2];   // (1024, 1024)
    const float* Wout  = (const float*)d_in[3];   // (1024, 1024)
    float* out = (float*)d_out;                   // (2, 2048, 1024) f32

    char* ws = (char*)d_ws;
    unsigned short* h_bf    = (unsigned short*)(ws);               // 8 MB
    unsigned short* Wval_bf = (unsigned short*)(ws +  8388608);    // 2 MB
    unsigned short* Wout_bf = (unsigned short*)(ws + 10485760);    // 2 MB
    unsigned short* hvT     = (unsigned short*)(ws + 12582912);    // 8 MB  [b*1024 + head*64 + d][m]
    unsigned short* att     = (unsigned short*)(ws + 20971520);    // 8 MB  (B, M, HS)
    float*          mean_   = (float*)(ws + 29360128);             // 256 KB
    float*          soft_   = (float*)(ws + 29622272);             // 256 KB

    // weight converts (one launch)
    cvt_w<<<2048, 256, 0, stream>>>(Wval, Wout, Wval_bf, Wout_bf);

    // span params + fused h convert
    span_proj<<<2 * MM, 256, 0, stream>>>(h, Wspan, mean_, soft_, h_bf);

    // value GEMM, transposed output: hvT[b*1024 + n][m] = sum_c Wval[n,c] * h[b,m,c]
    // A = Wval (1024 x 1024), B = h_b (2048 x 1024): grid (2048/64, 1024/128, 2) = 512 blocks
    gemm_bt<1><<<dim3(MM / 64, HSZ / 128, 2), 256, 0, stream>>>(
        Wval_bf, h_bf, hvT, MM, HSZ,
        0L, (long)MM * HSZ, (long)HSZ * MM);

    // fused Gaussian attention -> att (B, M, HS) bf16
    attn_gauss<<<dim3(MM / 64, 32), 256, 0, stream>>>(mean_, soft_, hvT, att);

    // output GEMM: out[b*2048+m][n] = sum_c att[b,m,c] * Wout[n,c]
    // A = att (4096 x 1024), B = Wout (1024 x 1024): grid (1024/64, 4096/128, 1) = 512 blocks
    gemm_bt<0><<<dim3(HSZ / 64, (2 * MM) / 128, 1), 256, 0, stream>>>(
        att, Wout_bf, out, HSZ, HSZ,
        0L, 0L, 0L);
}

// Round 3
// 108.361 us; speedup vs baseline: 1.0879x; 1.0172x over previous
//
#include <hip/hip_runtime.h>
#include <hip/hip_bf16.h>

// Problem constants (B=2, M=2048, HS=1024, K=16 heads, D=64)
#define MM   2048
#define HSZ  1024
#define KH   16
#define DH   64

typedef __attribute__((ext_vector_type(8))) short bf16x8;
typedef __attribute__((ext_vector_type(4))) float f32x4;
typedef __attribute__((ext_vector_type(8))) unsigned short u16x8;

#define GLOAD_LDS16(gp, lp) \
    __builtin_amdgcn_global_load_lds( \
        (const __attribute__((address_space(1))) unsigned int*)(gp), \
        (__attribute__((address_space(3))) unsigned int*)(lp), 16, 0, 0)

__device__ __forceinline__ unsigned short f2bf(float x) {
    union { float f; unsigned u; } v; v.f = x;
    unsigned r = v.u + 0x7FFFu + ((v.u >> 16) & 1u);
    return (unsigned short)(r >> 16);
}

// ---------------- weight converts, both in one launch ----------------
__global__ void cvt_w(const float* __restrict__ w0, const float* __restrict__ w1,
                      unsigned short* __restrict__ o0, unsigned short* __restrict__ o1) {
    int bid = blockIdx.x;
    const float* in = (bid < 1024) ? w0 : w1;
    unsigned short* out = (bid < 1024) ? o0 : o1;
    int i = ((bid & 1023) * 256 + threadIdx.x) * 4;
    float4 v = *(const float4*)(in + i);
    ushort4 o;
    o.x = f2bf(v.x); o.y = f2bf(v.y); o.z = f2bf(v.z); o.w = f2bf(v.w);
    *(ushort4*)(out + i) = o;
}

// ---------------- span projection (+ fused h f32->bf16 convert) ----------------
__global__ __launch_bounds__(256) void span_proj(
    const float* __restrict__ h, const float* __restrict__ Wspan,
    float* __restrict__ mean_, float* __restrict__ soft_,
    unsigned short* __restrict__ h_bf)
{
    __shared__ float hrow[HSZ];
    int row = blockIdx.x;            // b*2048 + m
    int b = row >> 11, m = row & 2047;
    int t = threadIdx.x;
    float4 hv = *(const float4*)&h[(long)row * HSZ + t * 4];
    *(float4*)&hrow[t * 4] = hv;
    ushort4 hb;
    hb.x = f2bf(hv.x); hb.y = f2bf(hv.y); hb.z = f2bf(hv.z); hb.w = f2bf(hv.w);
    *(ushort4*)&h_bf[(long)row * HSZ + t * 4] = hb;
    __syncthreads();
    int o = t >> 3, part = t & 7;    // 32 outputs x 8 threads
    const float* w = Wspan + o * HSZ;
    float4 s4 = {0.f, 0.f, 0.f, 0.f};
    #pragma unroll 8
    for (int i = 0; i < 32; ++i) {
        int c = part * 4 + i * 32;
        float4 a  = *(const float4*)&hrow[c];
        float4 wv = *(const float4*)&w[c];
        s4.x += a.x * wv.x; s4.y += a.y * wv.y;
        s4.z += a.z * wv.z; s4.w += a.w * wv.w;
    }
    float s = s4.x + s4.y + s4.z + s4.w;
    s += __shfl_xor(s, 1, 64);
    s += __shfl_xor(s, 2, 64);
    s += __shfl_xor(s, 4, 64);
    if (part == 0) {
        int k = o >> 1;
        int bk = b * KH + k;
        if ((o & 1) == 0) {
            mean_[bk * MM + m] = (1.f / (1.f + __expf(-s))) * (float)MM;
        } else {
            float sp = (s > 15.f) ? s : log1pf(__expf(s));
            soft_[bk * MM + m] = sp;
        }
    }
}

// ---------------- bf16 MFMA GEMM: C[i,j] = sum_k A[i,k]*B[j,k] ----------------
// 128x128 tile, BK=64, 256 threads (4 waves, 64x64 out each).
// Double-buffered 2-phase (stage k+1 at top, one barrier per step).
// LDS: linear gload_lds dest + XOR-swizzled SOURCE chunk; ds_read applies same XOR.
template<int STORE_BF16>
__global__ __launch_bounds__(256) void gemm_bt(
    const unsigned short* __restrict__ A, const unsigned short* __restrict__ Bm,
    void* __restrict__ Cv, int N, int Kd,
    long aZ, long bZ, long cZ)
{
    __shared__ __align__(16) unsigned short As[2][128 * 64];
    __shared__ __align__(16) unsigned short Bs[2][128 * 64];
    const unsigned short* Ab = A  + blockIdx.z * aZ;
    const unsigned short* Bb = Bm + blockIdx.z * bZ;
    long czoff = blockIdx.z * cZ;
    int row0 = blockIdx.y * 128;
    int col0 = blockIdx.x * 128;
    int t = threadIdx.x;
    int wid = t >> 6, l = t & 63;
    int wr = wid >> 1, wc = wid & 1;
    int lr = l & 15, lhi = l >> 4;

    // staging: 1024 16B-chunks per matrix, 4 per thread.
    // row r's chunk cc lands at slot (cc ^ (r&7)) -> read side XORs the same way.
    int lin0 = t, lin1 = t + 256, lin2 = t + 512, lin3 = t + 768;
    #define SROW(li) ((li) >> 3)
    #define SCOL(li) ((((li) & 7) ^ (SROW(li) & 7)) * 8)

    f32x4 acc[4][4] = {};
    int nk = Kd >> 6;

    #define STAGE(buf, k0s) do { \
        GLOAD_LDS16(Ab + (long)(row0 + SROW(lin0)) * Kd + (k0s) + SCOL(lin0), &As[buf][lin0 * 8]); \
        GLOAD_LDS16(Bb + (long)(col0 + SROW(lin0)) * Kd + (k0s) + SCOL(lin0), &Bs[buf][lin0 * 8]); \
        GLOAD_LDS16(Ab + (long)(row0 + SROW(lin1)) * Kd + (k0s) + SCOL(lin1), &As[buf][lin1 * 8]); \
        GLOAD_LDS16(Bb + (long)(col0 + SROW(lin1)) * Kd + (k0s) + SCOL(lin1), &Bs[buf][lin1 * 8]); \
        GLOAD_LDS16(Ab + (long)(row0 + SROW(lin2)) * Kd + (k0s) + SCOL(lin2), &As[buf][lin2 * 8]); \
        GLOAD_LDS16(Bb + (long)(col0 + SROW(lin2)) * Kd + (k0s) + SCOL(lin2), &Bs[buf][lin2 * 8]); \
        GLOAD_LDS16(Ab + (long)(row0 + SROW(lin3)) * Kd + (k0s) + SCOL(lin3), &As[buf][lin3 * 8]); \
        GLOAD_LDS16(Bb + (long)(col0 + SROW(lin3)) * Kd + (k0s) + SCOL(lin3), &Bs[buf][lin3 * 8]); \
    } while (0)

    STAGE(0, 0);
    __syncthreads();

    for (int ks = 0; ks < nk; ++ks) {
        int cur = ks & 1;
        if (ks + 1 < nk) STAGE(cur ^ 1, (ks + 1) << 6);
        #pragma unroll
        for (int kk = 0; kk < 64; kk += 32) {
            int slotx = (((kk >> 3) + lhi) ^ (lr & 7)) << 3;   // element offset of swizzled 8-chunk
            bf16x8 af[4], bfr[4];
            #pragma unroll
            for (int i = 0; i < 4; ++i)
                af[i] = *(const bf16x8*)&As[cur][(wr * 64 + i * 16 + lr) * 64 + slotx];
            #pragma unroll
            for (int j = 0; j < 4; ++j)
                bfr[j] = *(const bf16x8*)&Bs[cur][(wc * 64 + j * 16 + lr) * 64 + slotx];
            #pragma unroll
            for (int i = 0; i < 4; ++i)
                #pragma unroll
                for (int j = 0; j < 4; ++j)
                    acc[i][j] = __builtin_amdgcn_mfma_f32_16x16x32_bf16(af[i], bfr[j], acc[i][j], 0, 0, 0);
        }
        __syncthreads();   // drains the prefetch vmcnt + protects dbuf swap
    }

    // C/D layout: col = l&15, row = (l>>4)*4 + r_
    #pragma unroll
    for (int i = 0; i < 4; ++i) {
        int rbase = row0 + wr * 64 + i * 16 + lhi * 4;
        #pragma unroll
        for (int j = 0; j < 4; ++j) {
            int cidx = col0 + wc * 64 + j * 16 + lr;
            #pragma unroll
            for (int r_ = 0; r_ < 4; ++r_) {
                long idx = czoff + (long)(rbase + r_) * N + cidx;
                if (STORE_BF16) ((unsigned short*)Cv)[idx] = f2bf(acc[i][j][r_]);
                else            ((float*)Cv)[idx] = acc[i][j][r_];
            }
        }
    }
}

// ---------------- fused Gaussian attention: out = softmax(-soft*(j-mean)^2) @ V ----------------
// hvT: [b*1024 + head*64 + d][2048 j] bf16.  512 threads (8 waves), 128 q-rows/block.
// Grid flat 512 blocks, XCD-chunked so each XCD serves 4 heads (V L2-resident).
// V staged via gload_lds (linear dest, XOR-swizzled source), double-buffered.
__global__ __launch_bounds__(512) void attn_gauss(
    const float* __restrict__ mean_, const float* __restrict__ soft_,
    const unsigned short* __restrict__ hvT, unsigned short* __restrict__ att)
{
    __shared__ __align__(16) unsigned short Vs[2][64 * 64];
    int flat = blockIdx.x;                   // 0..511
    int swz = (flat & 7) * 64 + (flat >> 3); // XCD-chunked bijection
    int bk = swz >> 4;                       // 0..31
    int qb = swz & 15;                       // 0..15 (128 rows each)
    int t = threadIdx.x, wid = t >> 6, l = t & 63;
    int b = bk >> 4, head = bk & 15;
    int lr = l & 15, lhi = l >> 4;
    int q = qb * 128 + wid * 16 + lr;
    float mq  = mean_[bk * MM + q];
    float sq  = soft_[bk * MM + q];
    const unsigned short* Vbase = hvT + (long)bk * DH * MM;

    // staging: 512 chunks, 1 per thread
    int sr = t >> 3;
    int sc = (((t & 7) ^ (sr & 7)) * 8);

    f32x4 acc[4] = {};
    float lsum = 0.f;
    int jlane0 = lhi * 8;

    GLOAD_LDS16(Vbase + (long)sr * MM + sc, &Vs[0][t * 8]);
    __syncthreads();

    for (int kt = 0; kt < 32; ++kt) {
        int cur = kt & 1;
        int k0 = kt * 64;
        if (kt + 1 < 32)
            GLOAD_LDS16(Vbase + (long)sr * MM + (k0 + 64) + sc, &Vs[cur ^ 1][t * 8]);

        float dmin = fmaxf(fmaxf((float)k0 - mq, mq - (float)(k0 + 63)), 0.f);
        bool active = (sq * dmin * dmin) < 50.f;   // exp(-50) ~ 2e-22
        if (__ballot(active)) {
            #pragma unroll
            for (int kk = 0; kk < 64; kk += 32) {
                bf16x8 pfrag;
                float dbase = (float)(k0 + kk + jlane0) - mq;
                #pragma unroll
                for (int jj = 0; jj < 8; ++jj) {
                    float d_ = dbase + (float)jj;
                    float p = __expf(-sq * d_ * d_);
                    lsum += p;
                    pfrag[jj] = (short)f2bf(p);
                }
                int slotx = (((kk >> 3) + lhi) ^ (lr & 7)) << 3;
                #pragma unroll
                for (int df = 0; df < 4; ++df) {
                    bf16x8 vf = *(const bf16x8*)&Vs[cur][(df * 16 + lr) * 64 + slotx];
                    acc[df] = __builtin_amdgcn_mfma_f32_16x16x32_bf16(pfrag, vf, acc[df], 0, 0, 0);
                }
            }
        }
        __syncthreads();
    }

    lsum += __shfl_xor(lsum, 16, 64);
    lsum += __shfl_xor(lsum, 32, 64);

    int qrow_base = qb * 128 + wid * 16;
    #pragma unroll
    for (int r_ = 0; r_ < 4; ++r_) {
        int qr = lhi * 4 + r_;
        float inv = 1.f / __shfl(lsum, qr, 64);
        long orow = ((long)b * MM + (qrow_base + qr)) * HSZ + head * DH;
        #pragma unroll
        for (int df = 0; df < 4; ++df)
            att[orow + df * 16 + lr] = f2bf(acc[df][r_] * inv);
    }
}

extern "C" void kernel_launch(void* const* d_in, const int* in_sizes, int n_in,
                              void* d_out, int out_size, void* d_ws, size_t ws_size,
                              hipStream_t stream) {
    (void)in_sizes; (void)n_in; (void)out_size; (void)ws_size;
    const float* h     = (const float*)d_in[0];   // (2, 2048, 1024)
    const float* Wspan = (const float*)d_in[1];   // (32, 1024)
    const float* Wval  = (const float*)d_in[2];   // (1024, 1024)
    const float* Wout  = (const float*)d_in[3];   // (1024, 1024)
    float* out = (float*)d_out;                   // (2, 2048, 1024) f32

    char* ws = (char*)d_ws;
    unsigned short* h_bf    = (unsigned short*)(ws);               // 8 MB
    unsigned short* Wval_bf = (unsigned short*)(ws +  8388608);    // 2 MB
    unsigned short* Wout_bf = (unsigned short*)(ws + 10485760);    // 2 MB
    unsigned short* hvT     = (unsigned short*)(ws + 12582912);    // 8 MB  [b*1024 + head*64 + d][m]
    unsigned short* att     = (unsigned short*)(ws + 20971520);    // 8 MB  (B, M, HS)
    float*          mean_   = (float*)(ws + 29360128);             // 256 KB
    float*          soft_   = (float*)(ws + 29622272);             // 256 KB

    cvt_w<<<2048, 256, 0, stream>>>(Wval, Wout, Wval_bf, Wout_bf);

    span_proj<<<2 * MM, 256, 0, stream>>>(h, Wspan, mean_, soft_, h_bf);

    // value GEMM: hvT[b*1024 + n][m] = sum_c Wval[n,c] * h[b,m,c]
    gemm_bt<1><<<dim3(MM / 128, HSZ / 128, 2), 256, 0, stream>>>(
        Wval_bf, h_bf, hvT, MM, HSZ,
        0L, (long)MM * HSZ, (long)HSZ * MM);

    // fused Gaussian attention -> att (B, M, HS) bf16
    attn_gauss<<<512, 512, 0, stream>>>(mean_, soft_, hvT, att);

    // output GEMM: out[b*2048+m][n] = sum_c att[b,m,c] * Wout[n,c]
    gemm_bt<0><<<dim3(HSZ / 128, (2 * MM) / 128, 1), 256, 0, stream>>>(
        att, Wout_bf, out, HSZ, HSZ,
        0L, 0L, 0L);
}

// Round 4
// 86.595 us; speedup vs baseline: 1.3613x; 1.2514x over previous
//
#include <hip/hip_runtime.h>
#include <hip/hip_bf16.h>

// Problem constants (B=2, M=2048, HS=1024, K=16 heads, D=64)
#define MM   2048
#define HSZ  1024
#define KH   16
#define DH   64

typedef __attribute__((ext_vector_type(8))) short bf16x8;
typedef __attribute__((ext_vector_type(4))) float f32x4;
typedef __attribute__((ext_vector_type(8))) unsigned short u16x8;

#define GLOAD_LDS16(gp, lp) \
    __builtin_amdgcn_global_load_lds( \
        (const __attribute__((address_space(1))) unsigned int*)(gp), \
        (__attribute__((address_space(3))) unsigned int*)(lp), 16, 0, 0)

__device__ __forceinline__ unsigned short f2bf(float x) {
    union { float f; unsigned u; } v; v.f = x;
    unsigned r = v.u + 0x7FFFu + ((v.u >> 16) & 1u);
    return (unsigned short)(r >> 16);
}

// ---------------- weight converts, both in one launch ----------------
__global__ void cvt_w(const float* __restrict__ w0, const float* __restrict__ w1,
                      unsigned short* __restrict__ o0, unsigned short* __restrict__ o1) {
    int bid = blockIdx.x;
    const float* in = (bid < 1024) ? w0 : w1;
    unsigned short* out = (bid < 1024) ? o0 : o1;
    int i = ((bid & 1023) * 256 + threadIdx.x) * 4;
    float4 v = *(const float4*)(in + i);
    ushort4 o;
    o.x = f2bf(v.x); o.y = f2bf(v.y); o.z = f2bf(v.z); o.w = f2bf(v.w);
    *(ushort4*)(out + i) = o;
}

// ---------------- span projection: 8 rows/block, W_span amortized 8x ----------------
__global__ __launch_bounds__(256) void span_proj(
    const float* __restrict__ h, const float* __restrict__ Wspan,
    float* __restrict__ mean_, float* __restrict__ soft_,
    unsigned short* __restrict__ h_bf)
{
    __shared__ float hrow[8][HSZ];
    int row0 = blockIdx.x * 8;
    int t = threadIdx.x;
    // stage 8 h-rows + fused bf16 convert
    #pragma unroll
    for (int i = 0; i < 8; ++i) {
        int li = t + 256 * i;                // float4 id 0..2047
        int r = li >> 8, c4 = (li & 255) * 4;
        float4 hv = *(const float4*)&h[(long)(row0 + r) * HSZ + c4];
        *(float4*)&hrow[r][c4] = hv;
        ushort4 hb;
        hb.x = f2bf(hv.x); hb.y = f2bf(hv.y); hb.z = f2bf(hv.z); hb.w = f2bf(hv.w);
        *(ushort4*)&h_bf[(long)(row0 + r) * HSZ + c4] = hb;
    }
    __syncthreads();
    int o = t >> 3, part = t & 7;            // 32 outputs x 8 partial-lanes
    const float* w = Wspan + o * HSZ;
    float4 acc[8] = {};
    for (int i = 0; i < 32; ++i) {
        int c = part * 4 + i * 32;
        float4 wv = *(const float4*)&w[c];
        #pragma unroll
        for (int r = 0; r < 8; ++r) {
            float4 a = *(const float4*)&hrow[r][c];
            acc[r].x += a.x * wv.x; acc[r].y += a.y * wv.y;
            acc[r].z += a.z * wv.z; acc[r].w += a.w * wv.w;
        }
    }
    #pragma unroll
    for (int r = 0; r < 8; ++r) {
        float s = acc[r].x + acc[r].y + acc[r].z + acc[r].w;
        s += __shfl_xor(s, 1, 64);
        s += __shfl_xor(s, 2, 64);
        s += __shfl_xor(s, 4, 64);
        if (part == 0) {
            int m = row0 + r;
            int b = m >> 11, mm = m & 2047;
            int bk = b * KH + (o >> 1);
            if ((o & 1) == 0) {
                mean_[bk * MM + mm] = (1.f / (1.f + __expf(-s))) * (float)MM;
            } else {
                float sp = (s > 15.f) ? s : log1pf(__expf(s));
                soft_[bk * MM + mm] = sp;
            }
        }
    }
}

// ---------------- deterministic counting sort of rows by mean/64, per (b,head) ----------------
__global__ __launch_bounds__(256) void sort_rows(
    const float* __restrict__ mean_, int* __restrict__ perm)
{
    __shared__ unsigned short hist[32][257];
    __shared__ int binTot[32];
    __shared__ int binStart[32];
    int bk = blockIdx.x, t = threadIdx.x;
    int bins[8];
    #pragma unroll
    for (int i = 0; i < 8; ++i) {
        float mq = mean_[bk * MM + t * 8 + i];
        int b = (int)(mq * (1.f / 64.f));
        bins[i] = min(31, max(0, b));
    }
    for (int b = 0; b < 32; ++b) hist[b][t] = 0;
    __syncthreads();
    #pragma unroll
    for (int i = 0; i < 8; ++i) hist[bins[i]][t]++;   // own column, race-free
    __syncthreads();
    // per-bin exclusive prefix over threads (wave w handles bins w*8..w*8+7)
    int w = t >> 6, l = t & 63;
    for (int b = w * 8; b < w * 8 + 8; ++b) {
        int carry = 0;
        for (int g = 0; g < 4; ++g) {
            int v = (int)hist[b][g * 64 + l];
            int x = v;
            #pragma unroll
            for (int off = 1; off < 64; off <<= 1) {
                int y = __shfl_up(x, off, 64);
                if (l >= off) x += y;
            }
            hist[b][g * 64 + l] = (unsigned short)(x - v + carry);
            carry += __shfl(x, 63, 64);
        }
        if (l == 0) binTot[b] = carry;
    }
    __syncthreads();
    if (t == 0) {
        int s = 0;
        for (int b = 0; b < 32; ++b) { binStart[b] = s; s += binTot[b]; }
    }
    __syncthreads();
    #pragma unroll
    for (int i = 0; i < 8; ++i) {
        int b = bins[i];
        int prior = 0;
        #pragma unroll
        for (int j = 0; j < 8; ++j) if (j < i && bins[j] == b) prior++;
        int pos = binStart[b] + (int)hist[b][t] + prior;
        perm[bk * MM + pos] = t * 8 + i;
    }
}

// ---------------- bf16 MFMA GEMM: C[i,j] = sum_k A[i,k]*B[j,k] ----------------
// 128(M) x 64(N) tile, BK=64, 256 threads (4 waves 2x2, wave tile 64x32).
// Counted-vmcnt double-buffer pipeline: never drain to 0 in the main loop.
template<int STORE_BF16>
__global__ __launch_bounds__(256) void gemm_bt(
    const unsigned short* __restrict__ A, const unsigned short* __restrict__ Bm,
    void* __restrict__ Cv, int N, int Kd,
    long aZ, long bZ, long cZ)
{
    __shared__ __align__(16) unsigned short As[2][128 * 64];
    __shared__ __align__(16) unsigned short Bs[2][64 * 64];
    const unsigned short* Ab = A  + blockIdx.z * aZ;
    const unsigned short* Bb = Bm + blockIdx.z * bZ;
    long czoff = blockIdx.z * cZ;
    int row0 = blockIdx.y * 128;
    int col0 = blockIdx.x * 64;
    int t = threadIdx.x;
    int wid = t >> 6, l = t & 63;
    int wr = wid >> 1, wc = wid & 1;
    int lr = l & 15, lhi = l >> 4;

    // staging chunk li -> row li>>3, src chunk (li&7)^(row&7), linear LDS dest
    #define SROW(li) ((li) >> 3)
    #define SCOL(li) ((((li) & 7) ^ (SROW(li) & 7)) * 8)
    #define STAGE(buf, k0s) do { \
        int a0 = t, a1 = t + 256, a2 = t + 512, a3 = t + 768; \
        GLOAD_LDS16(Ab + (long)(row0 + SROW(a0)) * Kd + (k0s) + SCOL(a0), &As[buf][a0 * 8]); \
        GLOAD_LDS16(Ab + (long)(row0 + SROW(a1)) * Kd + (k0s) + SCOL(a1), &As[buf][a1 * 8]); \
        GLOAD_LDS16(Ab + (long)(row0 + SROW(a2)) * Kd + (k0s) + SCOL(a2), &As[buf][a2 * 8]); \
        GLOAD_LDS16(Ab + (long)(row0 + SROW(a3)) * Kd + (k0s) + SCOL(a3), &As[buf][a3 * 8]); \
        GLOAD_LDS16(Bb + (long)(col0 + SROW(a0)) * Kd + (k0s) + SCOL(a0), &Bs[buf][a0 * 8]); \
        GLOAD_LDS16(Bb + (long)(col0 + SROW(a1)) * Kd + (k0s) + SCOL(a1), &Bs[buf][a1 * 8]); \
    } while (0)

    f32x4 acc[4][2] = {};
    int nk = Kd >> 6;

    STAGE(0, 0);

    for (int ks = 0; ks < nk; ++ks) {
        int cur = ks & 1;
        if (ks + 1 < nk) {
            STAGE(cur ^ 1, (ks + 1) << 6);
            asm volatile("s_waitcnt vmcnt(6)" ::: "memory");   // tile ks retired, 6 in flight
        } else {
            asm volatile("s_waitcnt vmcnt(0)" ::: "memory");
        }
        __builtin_amdgcn_s_barrier();

        bf16x8 af[2][4], bfr[2][2];
        #pragma unroll
        for (int kk = 0; kk < 2; ++kk) {
            int slotx = ((kk * 4 + lhi) ^ (lr & 7)) << 3;
            #pragma unroll
            for (int i = 0; i < 4; ++i)
                af[kk][i] = *(const bf16x8*)&As[cur][(wr * 64 + i * 16 + lr) * 64 + slotx];
            #pragma unroll
            for (int j = 0; j < 2; ++j)
                bfr[kk][j] = *(const bf16x8*)&Bs[cur][(wc * 32 + j * 16 + lr) * 64 + slotx];
        }
        asm volatile("s_waitcnt lgkmcnt(0)" ::: "memory");
        __builtin_amdgcn_sched_barrier(0);
        __builtin_amdgcn_s_barrier();     // all waves done reading buf cur -> next STAGE may overwrite

        #pragma unroll
        for (int kk = 0; kk < 2; ++kk)
            #pragma unroll
            for (int i = 0; i < 4; ++i)
                #pragma unroll
                for (int j = 0; j < 2; ++j)
                    acc[i][j] = __builtin_amdgcn_mfma_f32_16x16x32_bf16(af[kk][i], bfr[kk][j], acc[i][j], 0, 0, 0);
    }

    // C/D layout: col = l&15, row = (l>>4)*4 + r_
    #pragma unroll
    for (int i = 0; i < 4; ++i) {
        int rbase = row0 + wr * 64 + i * 16 + lhi * 4;
        #pragma unroll
        for (int j = 0; j < 2; ++j) {
            int cidx = col0 + wc * 32 + j * 16 + lr;
            #pragma unroll
            for (int r_ = 0; r_ < 4; ++r_) {
                long idx = czoff + (long)(rbase + r_) * N + cidx;
                if (STORE_BF16) ((unsigned short*)Cv)[idx] = f2bf(acc[i][j][r_]);
                else            ((float*)Cv)[idx] = acc[i][j][r_];
            }
        }
    }
}

// ---------------- fused Gaussian attention over mean-sorted rows ----------------
// hvT: [b*1024 + head*64 + d][2048 j] bf16.  512 threads (8 waves), 128 sorted rows/block.
__global__ __launch_bounds__(512) void attn_gauss(
    const float* __restrict__ mean_, const float* __restrict__ soft_,
    const int* __restrict__ perm,
    const unsigned short* __restrict__ hvT, unsigned short* __restrict__ att)
{
    __shared__ __align__(16) unsigned short Vs[2][64 * 64];
    int flat = blockIdx.x;                   // 0..511
    int swz = (flat & 7) * 64 + (flat >> 3); // XCD-chunked bijection
    int bk = swz >> 4;                       // 0..31
    int qb = swz & 15;                       // 0..15
    int t = threadIdx.x, wid = t >> 6, l = t & 63;
    int b = bk >> 4, head = bk & 15;
    int lr = l & 15, lhi = l >> 4;
    int slot = qb * 128 + wid * 16 + lr;
    int q = perm[bk * MM + slot];
    float mq  = mean_[bk * MM + q];
    float sq  = soft_[bk * MM + q];
    const unsigned short* Vbase = hvT + (long)bk * DH * MM;

    int sr = t >> 3;
    int sc = (((t & 7) ^ (sr & 7)) * 8);

    f32x4 acc[4] = {};
    float lsum = 0.f;
    int jlane0 = lhi * 8;

    GLOAD_LDS16(Vbase + (long)sr * MM + sc, &Vs[0][t * 8]);
    __syncthreads();

    for (int kt = 0; kt < 32; ++kt) {
        int cur = kt & 1;
        int k0 = kt * 64;
        if (kt + 1 < 32)
            GLOAD_LDS16(Vbase + (long)sr * MM + (k0 + 64) + sc, &Vs[cur ^ 1][t * 8]);

        float dmin = fmaxf(fmaxf((float)k0 - mq, mq - (float)(k0 + 63)), 0.f);
        bool active = (sq * dmin * dmin) < 50.f;   // exp(-50) ~ 2e-22
        if (__ballot(active)) {
            #pragma unroll
            for (int kk = 0; kk < 64; kk += 32) {
                bf16x8 pfrag;
                float dbase = (float)(k0 + kk + jlane0) - mq;
                #pragma unroll
                for (int jj = 0; jj < 8; ++jj) {
                    float d_ = dbase + (float)jj;
                    float p = __expf(-sq * d_ * d_);
                    lsum += p;
                    pfrag[jj] = (short)f2bf(p);
                }
                int slotx = (((kk >> 3) + lhi) ^ (lr & 7)) << 3;
                #pragma unroll
                for (int df = 0; df < 4; ++df) {
                    bf16x8 vf = *(const bf16x8*)&Vs[cur][(df * 16 + lr) * 64 + slotx];
                    acc[df] = __builtin_amdgcn_mfma_f32_16x16x32_bf16(pfrag, vf, acc[df], 0, 0, 0);
                }
            }
        }
        __syncthreads();
    }

    lsum += __shfl_xor(lsum, 16, 64);
    lsum += __shfl_xor(lsum, 32, 64);

    int slot_base = qb * 128 + wid * 16;
    #pragma unroll
    for (int r_ = 0; r_ < 4; ++r_) {
        int qr = lhi * 4 + r_;
        float inv = 1.f / __shfl(lsum, qr, 64);
        int qo = perm[bk * MM + slot_base + qr];
        long orow = ((long)b * MM + qo) * HSZ + head * DH;
        #pragma unroll
        for (int df = 0; df < 4; ++df)
            att[orow + df * 16 + lr] = f2bf(acc[df][r_] * inv);
    }
}

extern "C" void kernel_launch(void* const* d_in, const int* in_sizes, int n_in,
                              void* d_out, int out_size, void* d_ws, size_t ws_size,
                              hipStream_t stream) {
    (void)in_sizes; (void)n_in; (void)out_size; (void)ws_size;
    const float* h     = (const float*)d_in[0];   // (2, 2048, 1024)
    const float* Wspan = (const float*)d_in[1];   // (32, 1024)
    const float* Wval  = (const float*)d_in[2];   // (1024, 1024)
    const float* Wout  = (const float*)d_in[3];   // (1024, 1024)
    float* out = (float*)d_out;                   // (2, 2048, 1024) f32

    char* ws = (char*)d_ws;
    unsigned short* h_bf    = (unsigned short*)(ws);               // 8 MB
    unsigned short* Wval_bf = (unsigned short*)(ws +  8388608);    // 2 MB
    unsigned short* Wout_bf = (unsigned short*)(ws + 10485760);    // 2 MB
    unsigned short* hvT     = (unsigned short*)(ws + 12582912);    // 8 MB
    unsigned short* att     = (unsigned short*)(ws + 20971520);    // 8 MB
    float*          mean_   = (float*)(ws + 29360128);             // 256 KB
    float*          soft_   = (float*)(ws + 29622272);             // 256 KB
    int*            perm    = (int*)(ws + 29884416);               // 256 KB

    cvt_w<<<2048, 256, 0, stream>>>(Wval, Wout, Wval_bf, Wout_bf);

    span_proj<<<512, 256, 0, stream>>>(h, Wspan, mean_, soft_, h_bf);

    sort_rows<<<32, 256, 0, stream>>>(mean_, perm);

    // value GEMM: hvT[b*1024 + n][m] = sum_c Wval[n,c] * h[b,m,c]
    gemm_bt<1><<<dim3(MM / 64, HSZ / 128, 2), 256, 0, stream>>>(
        Wval_bf, h_bf, hvT, MM, HSZ,
        0L, (long)MM * HSZ, (long)HSZ * MM);

    // fused Gaussian attention -> att (B, M, HS) bf16
    attn_gauss<<<512, 512, 0, stream>>>(mean_, soft_, perm, hvT, att);

    // output GEMM: out[b*2048+m][n] = sum_c att[b,m,c] * Wout[n,c]
    gemm_bt<0><<<dim3(HSZ / 64, (2 * MM) / 128, 1), 256, 0, stream>>>(
        att, Wout_bf, out, HSZ, HSZ,
        0L, 0L, 0L);
}